// Round 7
// baseline (130.197 us; speedup 1.0000x reference)
//
#include <hip/hip_runtime.h>

#define BSZ 8
#define NQ 2048
#define MP 64
#define DD 1024
#define K2ALL 2048       // interleaved ushort per (b,m) row: [m2, -2*m2*p]
#define BN 32            // query rows per block (2 n-subtiles per wave)
#define LQS 520          // quarter-K: 512 interleaved ushorts (256 d) + 8 pad
#define NSTEP 64         // total k32 steps
#define NTILES (NQ / BN) // 64

typedef __bf16 bf16x8 __attribute__((ext_vector_type(8)));
typedef float f32x4 __attribute__((ext_vector_type(4)));
typedef unsigned short us8 __attribute__((ext_vector_type(8)));

__device__ __forceinline__ unsigned short f2bf(float f) {
    union { float f; unsigned int u; } v; v.f = f;
    unsigned int u = v.u;
    return (unsigned short)((u + 0x7FFFu + ((u >> 16) & 1u)) >> 16);  // RNE
}

// Pass 1: pack proto/mask -> bf16 [m2, -2*m2*p] in MFMA fragment order +
// fp32 pterm. Flat ushort index: ((((b*4+mt)*64 + s)*64) + lane)*8 + e,
// mt=m>>4, s=k32-step (t>>2), lane=(t&3)*16 + (m&15). One wave-step B-load
// in the main kernel = one contiguous 1 KB.
__global__ __launch_bounds__(256) void pack_kernel(
    const float* __restrict__ proto,
    const float* __restrict__ mask,
    unsigned short* __restrict__ Pf,
    float* __restrict__ Pterm)
{
    const int row = blockIdx.x;          // b*64 + m
    const int m = row & 63;
    const int b = row >> 6;
    const int t = threadIdx.x;           // d = 4t..4t+3 -> interleaved k = 8t..8t+7

    const float4 mk = *(const float4*)(mask  + (size_t)row * DD + 4 * t);
    const float4 pr = *(const float4*)(proto + (size_t)row * DD + 4 * t);

    const float m2x = mk.x * mk.x, m2y = mk.y * mk.y,
                m2z = mk.z * mk.z, m2w = mk.w * mk.w;
    const float ax = mk.x * pr.x, ay = mk.y * pr.y,
                az = mk.z * pr.z, aw = mk.w * pr.w;
    float pacc = ax * ax + ay * ay + az * az + aw * aw;

    us8 o;
    o[0] = f2bf(m2x); o[1] = f2bf(-2.f * m2x * pr.x);
    o[2] = f2bf(m2y); o[3] = f2bf(-2.f * m2y * pr.y);
    o[4] = f2bf(m2z); o[5] = f2bf(-2.f * m2z * pr.z);
    o[6] = f2bf(m2w); o[7] = f2bf(-2.f * m2w * pr.w);

    const int mt   = m >> 4;
    const int s    = t >> 2;
    const int lane = (t & 3) * 16 + (m & 15);
    const size_t idx = ((((size_t)(b * 4 + mt)) * 64 + s) * 64 + lane) * 8;
    *(us8*)(Pf + idx) = o;

    __shared__ float red[4];
    #pragma unroll
    for (int off = 32; off > 0; off >>= 1)
        pacc += __shfl_down(pacc, off, 64);
    const int lane64 = t & 63, w = t >> 6;
    if (lane64 == 0) red[w] = pacc;
    __syncthreads();
    if (t == 0) Pterm[row] = red[0] + red[1] + red[2] + red[3];
}

// Pass 2: 512 blocks (b = bid&7 -> XCD-affine, all co-resident), 256 threads.
// BN=32: per B-load each wave does 2 MFMAs (two n-subtiles) -> B L2 traffic
// halves to 128 MB. Query staged in 4 quarter-K stages (33 KB LDS); next
// quarter's loads issue right after each barrier and fly under compute.
__global__ __launch_bounds__(256, 2) void proto_main_kernel(
    const float* __restrict__ query,
    const unsigned short* __restrict__ Pf,
    const float* __restrict__ Pterm,
    const float* __restrict__ scale,
    float* __restrict__ out)
{
    __shared__ unsigned short Qs[BN][LQS];   // 33.3 KB

    const int tid = threadIdx.x;
    const int bid = blockIdx.x;
    const int b  = bid & 7;
    const int n0 = (bid >> 3) * BN;

    // staging map: row = tid>>3 (0..31), 8 threads x 8 float4 per row-stage
    const int qr  = tid >> 3;
    const int qc8 = tid & 7;
    const float* qptr = query + ((size_t)b * NQ + n0 + qr) * DD + 32 * qc8;

    const int lane = tid & 63;
    const int wid  = tid >> 6;           // m-tile owner
    const int lrow = lane & 15;
    const int lq   = (lane >> 4) * 8;
    const int mcol = 16 * wid + lrow;

    const unsigned short* bbase =
        Pf + (((size_t)(b * 4 + wid)) * 64) * 512 + (size_t)lane * 8;

    // ---- prime B queue: 8 KB/wave in flight before anything else ----
    bf16x8 bq[8];
    #pragma unroll
    for (int i = 0; i < 8; ++i)
        bq[i] = *(const bf16x8*)(bbase + (size_t)i * 512);

    // ---- load stage-0 query quarter ----
    float4 qv[8];
    #pragma unroll
    for (int p = 0; p < 8; ++p)
        qv[p] = *(const float4*)(qptr + 4 * p);

    const float pt = Pterm[b * MP + mcol];
    const float sc = scale[0] * (1.0f / (float)DD);

    f32x4 acc0 = (f32x4){0.f, 0.f, 0.f, 0.f};
    f32x4 acc1 = (f32x4){0.f, 0.f, 0.f, 0.f};

    #pragma unroll
    for (int stage = 0; stage < 4; ++stage) {
        // ---- stage the quarter (qv loaded during previous compute) ----
        #pragma unroll
        for (int p = 0; p < 8; ++p) {
            const float4 q = qv[p];
            us8 o;
            o[0] = f2bf(q.x * q.x); o[1] = f2bf(q.x);
            o[2] = f2bf(q.y * q.y); o[3] = f2bf(q.y);
            o[4] = f2bf(q.z * q.z); o[5] = f2bf(q.z);
            o[6] = f2bf(q.w * q.w); o[7] = f2bf(q.w);
            *(us8*)(&Qs[qr][64 * qc8 + 8 * p]) = o;
        }
        __syncthreads();

        // ---- issue next quarter's loads; they land during this compute ----
        if (stage < 3) {
            const float* qn = qptr + 256 * (stage + 1);
            #pragma unroll
            for (int p = 0; p < 8; ++p)
                qv[p] = *(const float4*)(qn + 4 * p);
        }

        // ---- 16 k-steps: 1 B-load, 2 A ds_reads, 2 MFMAs each ----
        #pragma unroll
        for (int g = 0; g < 16; ++g) {
            const int sg = 16 * stage + g;
            const bf16x8 bb = bq[sg & 7];
            if (sg + 8 < NSTEP)
                bq[sg & 7] = *(const bf16x8*)(bbase + (size_t)(sg + 8) * 512);
            const bf16x8 a0 = *(const bf16x8*)(&Qs[lrow][32 * g + lq]);
            const bf16x8 a1 = *(const bf16x8*)(&Qs[16 + lrow][32 * g + lq]);
            acc0 = __builtin_amdgcn_mfma_f32_16x16x32_bf16(a0, bb, acc0, 0, 0, 0);
            acc1 = __builtin_amdgcn_mfma_f32_16x16x32_bf16(a1, bb, acc1, 0, 0, 0);
        }
        if (stage < 3) __syncthreads();   // WAR before re-staging
    }

    // ---- epilogue: n = n0 + 16*sub + (lane>>4)*4 + r, m = mcol ----
    const size_t ob0 =
        ((size_t)b * NQ + (size_t)(n0 + (lane >> 4) * 4)) * MP + mcol;
    #pragma unroll
    for (int r = 0; r < 4; ++r)
        out[ob0 + (size_t)r * MP] = (acc0[r] + pt) * sc;
    const size_t ob1 = ob0 + (size_t)16 * MP;
    #pragma unroll
    for (int r = 0; r < 4; ++r)
        out[ob1 + (size_t)r * MP] = (acc1[r] + pt) * sc;
}

extern "C" void kernel_launch(void* const* d_in, const int* in_sizes, int n_in,
                              void* d_out, int out_size, void* d_ws, size_t ws_size,
                              hipStream_t stream) {
    (void)in_sizes; (void)n_in; (void)ws_size; (void)out_size;
    const float* proto = (const float*)d_in[0];
    const float* mask  = (const float*)d_in[1];
    const float* query = (const float*)d_in[2];
    const float* scale = (const float*)d_in[5];
    float* out = (float*)d_out;

    unsigned short* Pf = (unsigned short*)d_ws;                           // 2 MiB
    float* Pterm = (float*)((char*)d_ws + (size_t)BSZ * MP * K2ALL * 2);  // +2 KiB

    pack_kernel<<<dim3(BSZ * MP), dim3(256), 0, stream>>>(proto, mask, Pf, Pterm);
    proto_main_kernel<<<dim3(BSZ * NTILES), dim3(256), 0, stream>>>(
        query, Pf, Pterm, scale, out);
}